// Round 12
// baseline (284.019 us; speedup 1.0000x reference)
//
#include <hip/hip_runtime.h>

#define BIG_NEG_F (-4294967296.0f)

typedef __attribute__((ext_vector_type(8))) short bf16x8;
typedef __attribute__((ext_vector_type(4))) float f32x4;

__device__ __forceinline__ float wave_sum(float v) {
#pragma unroll
    for (int m = 32; m; m >>= 1) v += __shfl_xor(v, m, 64);
    return v;
}
__device__ __forceinline__ float wave_max(float v) {
#pragma unroll
    for (int m = 32; m; m >>= 1) v = fmaxf(v, __shfl_xor(v, m, 64));
    return v;
}

__device__ __forceinline__ unsigned int pack2(float a, float b) {
    return (__float_as_uint(b) & 0xffff0000u) | (__float_as_uint(a) >> 16);
}
__device__ __forceinline__ float hipart(float x) {
    return __uint_as_float(__float_as_uint(x) & 0xffff0000u);
}
// truncation split: hi = bf16-truncate(v), lo = bf16-truncate(v - hi). Same math as r11.
__device__ __forceinline__ void split1(float v, unsigned short* hp, unsigned short* lp) {
    unsigned int hu = __float_as_uint(v) & 0xffff0000u;
    *hp = (unsigned short)(hu >> 16);
    *lp = (unsigned short)(__float_as_uint(v - __uint_as_float(hu)) >> 16);
}

// Fused: detect mask layout, x = seq*keep, q = ln1(x); also emit bf16 hi/lo pairs of
// x and q (direct-fragment GEMM operands). One block per row.
__global__ __launch_bounds__(256) void prep_ln_kernel(const float* __restrict__ seq,
                                                      const unsigned char* __restrict__ mraw,
                                                      unsigned char* __restrict__ mout,
                                                      float* __restrict__ X, float* __restrict__ Q,
                                                      const float* __restrict__ g,
                                                      const float* __restrict__ be,
                                                      unsigned short* __restrict__ Xh,
                                                      unsigned short* __restrict__ Xl,
                                                      unsigned short* __restrict__ Qh,
                                                      unsigned short* __restrict__ Ql) {
    __shared__ int flags[2];
    __shared__ float ws[8];
    int row = blockIdx.x, tid = threadIdx.x;
    if (tid == 0) { flags[0] = 0; flags[1] = 0; }
    __syncthreads();
    for (int i = tid; i < 2048; i += 256) {
        if (mraw[i]) {
            if (i & 3) atomicOr(&flags[0], 1);
            else if (i & 4) atomicOr(&flags[1], 1);
        }
    }
    __syncthreads();
    int mode = flags[0] ? 0 : (flags[1] ? 1 : 2);  // 0=u8, 1=i32, 2=i64
    unsigned char mrow = (mode == 0) ? mraw[row] : (mode == 1) ? mraw[row * 4] : mraw[row * 8];
    if (tid == 0) mout[row] = mrow ? 1 : 0;
    int idx = row * 256 + tid;
    int w = tid >> 6, lane = tid & 63;
    float v = mrow ? 0.f : seq[idx];
    X[idx] = v;
    split1(v, &Xh[idx], &Xl[idx]);
    float s = wave_sum(v);
    if (lane == 0) ws[w] = s;
    __syncthreads();
    float mean = (ws[0] + ws[1] + ws[2] + ws[3]) * (1.f / 256.f);
    float d = v - mean;
    float s2 = wave_sum(d * d);
    if (lane == 0) ws[4 + w] = s2;
    __syncthreads();
    float var = (ws[4] + ws[5] + ws[6] + ws[7]) * (1.f / 256.f);
    float qv = d / sqrtf(var + 1e-8f) * g[tid] + be[tid];
    Q[idx] = qv;
    split1(qv, &Qh[idx], &Ql[idx]);
}

// row layernorm over H=256; optional bf16 hi/lo outputs (null for final LN).
__global__ __launch_bounds__(256) void ln_kernel(const float* __restrict__ X, float* __restrict__ Y,
                                                 const float* __restrict__ g,
                                                 const float* __restrict__ be,
                                                 unsigned short* __restrict__ Yh,
                                                 unsigned short* __restrict__ Yl) {
    __shared__ float ws[8];
    int row = blockIdx.x, tid = threadIdx.x;
    int idx = row * 256 + tid;
    int w = tid >> 6, lane = tid & 63;
    float v = X[idx];
    float s = wave_sum(v);
    if (lane == 0) ws[w] = s;
    __syncthreads();
    float mean = (ws[0] + ws[1] + ws[2] + ws[3]) * (1.f / 256.f);
    float d = v - mean;
    float s2 = wave_sum(d * d);
    if (lane == 0) ws[4 + w] = s2;
    __syncthreads();
    float var = (ws[4] + ws[5] + ws[6] + ws[7]) * (1.f / 256.f);
    float yv = d / sqrtf(var + 1e-8f) * g[tid] + be[tid];
    Y[idx] = yv;
    if (Yh) split1(yv, &Yh[idx], &Yl[idx]);
}

struct SplitJob { const float* src; unsigned short* h; unsigned short* l; };

// Split the 5 weight tensors (each [2 layers,256,256] = 131072 floats) into bf16 hi/lo.
// grid (128,1,5), 1024 floats/block.
__global__ __launch_bounds__(256) void splitw_kernel(SplitJob s0, SplitJob s1, SplitJob s2,
                                                     SplitJob s3, SplitJob s4) {
    SplitJob S = (blockIdx.z == 0) ? s0 : (blockIdx.z == 1) ? s1 : (blockIdx.z == 2) ? s2
               : (blockIdx.z == 3) ? s3 : s4;
    int i = (blockIdx.x * 256 + threadIdx.x) * 4;
    float4 v = *(const float4*)(S.src + i);
    uint2 h, l;
    h.x = pack2(v.x, v.y); h.y = pack2(v.z, v.w);
    l.x = pack2(v.x - hipart(v.x), v.y - hipart(v.y));
    l.y = pack2(v.z - hipart(v.z), v.w - hipart(v.w));
    *(uint2*)(S.h + i) = h;
    *(uint2*)(S.l + i) = l;
}

struct GemmJob {
    const unsigned short* Ah;  // [2048,256] bf16-hi
    const unsigned short* Al;  //            bf16-lo
    const unsigned short* Wh;  // [256,256] (out,in) bf16-hi
    const unsigned short* Wl;
    const float* bias;
    const float* pos;          // per-position add, or null
    const float* res;          // residual add, or null
    const unsigned char* maskm;
    float* C;
    unsigned short* Ch;        // optional bf16 outputs (next GEMM's A operand)
    unsigned short* Cl;
    int relu;
};

// Direct-fragment MFMA GEMM: NO LDS, NO barriers. Operands pre-split to bf16 hi/lo in
// global; each wave computes one 16x16 output tile: 8 K-steps x {4 global 16B fragment
// loads + 3 MFMAs} (split-precision A·B ≈ Ah·Bh + Ah·Bl + Al·Bh). Fragment layout
// (HW-verified r11): A row=lane&15, k=(lane>>4)*8+j; B col=lane&15 same k; C/D
// col=lane&15, row=(lane>>4)*4+rr. 2048 waves/GEMM (8/CU FFN, 24/CU QKV) — loads
// pipeline freely across the unrolled loop with no sync points.
__global__ __launch_bounds__(256) void gemm_frag_kernel(GemmJob j0, GemmJob j1, GemmJob j2) {
    GemmJob J = (blockIdx.z == 0) ? j0 : (blockIdx.z == 1 ? j1 : j2);
    int tid = threadIdx.x, w = tid >> 6, lane = tid & 63;
    int n0 = blockIdx.x * 16;              // 16 N-tiles
    int m0 = blockIdx.y * 64 + w * 16;     // 32 M-blocks x 4 waves
    int r15 = lane & 15, kq = (lane >> 4) * 8;
    const unsigned short* Arh = J.Ah + (m0 + r15) * 256 + kq;
    const unsigned short* Arl = J.Al + (m0 + r15) * 256 + kq;
    const unsigned short* Brh = J.Wh + (n0 + r15) * 256 + kq;
    const unsigned short* Brl = J.Wl + (n0 + r15) * 256 + kq;
    f32x4 acc = {0.f, 0.f, 0.f, 0.f};
#pragma unroll
    for (int k = 0; k < 256; k += 32) {
        bf16x8 ah = *(const bf16x8*)(Arh + k);
        bf16x8 al = *(const bf16x8*)(Arl + k);
        bf16x8 bh = *(const bf16x8*)(Brh + k);
        bf16x8 bl = *(const bf16x8*)(Brl + k);
        acc = __builtin_amdgcn_mfma_f32_16x16x32_bf16(ah, bh, acc, 0, 0, 0);
        acc = __builtin_amdgcn_mfma_f32_16x16x32_bf16(ah, bl, acc, 0, 0, 0);
        acc = __builtin_amdgcn_mfma_f32_16x16x32_bf16(al, bh, acc, 0, 0, 0);
    }
    int col = n0 + r15;
    float bcol = J.bias[col];
    int rowb = m0 + (lane >> 4) * 4;
#pragma unroll
    for (int rr = 0; rr < 4; ++rr) {
        int m = rowb + rr;
        float v = acc[rr] + bcol;
        if (J.pos) v += J.pos[(m & 255) * 256 + col];
        if (J.relu) v = fmaxf(v, 0.f);
        if (J.res) v += J.res[m * 256 + col];
        if (J.maskm && J.maskm[m]) v = 0.f;
        J.C[m * 256 + col] = v;
        if (J.Ch) split1(v, &J.Ch[m * 256 + col], &J.Cl[m * 256 + col]);
    }
}

// 2048 one-qpos blocks. b = bid&7 keeps XCD affinity (working set ~2.3MB fits 4MiB
// private L2; FETCH 51->9.3MB measured). qpos map per-CU balanced (each CU's 8 blocks
// sum to exactly 1028 rows). Batch-2 inner loops: fits 64-VGPR budget of (256,8) with
// no scratch (batch-4 spills — verified r1/2/4/6). Epilogue also emits x2 bf16 hi/lo.
__global__ __launch_bounds__(256, 8) void attn_kernel(
    const float* __restrict__ Q, const float* __restrict__ Kp, const float* __restrict__ Vp,
    const float* __restrict__ qres, const int* __restrict__ tm,
    const float* __restrict__ tK, const float* __restrict__ tV,
    const float* __restrict__ g2, const float* __restrict__ b2,
    float* __restrict__ X2, unsigned short* __restrict__ X2h,
    unsigned short* __restrict__ X2l) {
    int bid = (int)blockIdx.x;
    int b = bid & 7;                    // XCD-aligned batch
    int i6 = bid >> 3;                  // 0..255
    int jj6 = i6 & 31, a6 = i6 >> 5;
    int q0m = jj6 * 4 + (a6 >> 1);      // 0..127
    int qpos = (a6 & 1) ? q0m : 255 - q0m;
    int tid = threadIdx.x, w = tid >> 6, lane = tid & 63;
    __shared__ float qrow[256];
    __shared__ int   stm[256];
    __shared__ float p[4][264];     // 264: writer lanes spread banks
    __shared__ float opart[4][256];
    __shared__ float denom[4];
    __shared__ float lnws[8];

    int rowbase = (b * 256 + qpos) * 256;
    qrow[tid] = Q[rowbase + tid];
    {
        int t = tm[rowbase + tid];
        stm[tid] = t < 0 ? 0 : (t > 512 ? 512 : t);
    }
    __syncthreads();

    // --- phase 1: scores, k ≡ w (mod 4) per wave — balanced across waves; batch-2
    {
        int h = lane >> 4;
        const float* qr = qrow + lane * 4;
        float q0 = qr[0], q1 = qr[1], q2 = qr[2], q3 = qr[3];
        const float* Kb  = Kp + (size_t)(b << 8) * 256 + lane * 4;
        const float* tKb = tK + lane * 4;
        int nact = (qpos >= w) ? ((qpos - w) >> 2) + 1 : 0;  // #k in {w, w+4, ...} <= qpos
        int i = 0;
        for (; i + 2 <= nact; i += 2) {
            int k0 = w + 4 * i;          // rows k0, k0+4
            float4 kv0 = *(const float4*)(Kb + (k0    ) * 256);
            float4 kv1 = *(const float4*)(Kb + (k0 + 4) * 256);
            float4 t0 = *(const float4*)(tKb + stm[k0    ] * 256);
            float4 t1 = *(const float4*)(tKb + stm[k0 + 4] * 256);
            float s0 = q0 * (kv0.x + t0.x) + q1 * (kv0.y + t0.y) + q2 * (kv0.z + t0.z) + q3 * (kv0.w + t0.w);
            float s1 = q0 * (kv1.x + t1.x) + q1 * (kv1.y + t1.y) + q2 * (kv1.z + t1.z) + q3 * (kv1.w + t1.w);
            s0 += __shfl_xor(s0, 1, 64); s1 += __shfl_xor(s1, 1, 64);
            s0 += __shfl_xor(s0, 2, 64); s1 += __shfl_xor(s1, 2, 64);
            s0 += __shfl_xor(s0, 4, 64); s1 += __shfl_xor(s1, 4, 64);
            s0 += __shfl_xor(s0, 8, 64); s1 += __shfl_xor(s1, 8, 64);
            if ((lane & 15) == 0) {
                p[h][k0    ] = s0 * 0.125f;
                p[h][k0 + 4] = s1 * 0.125f;
            }
        }
        if (i < nact) {
            int k = w + 4 * i;
            float4 kv = *(const float4*)(Kb + k * 256);
            float4 t4 = *(const float4*)(tKb + stm[k] * 256);
            float s = q0 * (kv.x + t4.x) + q1 * (kv.y + t4.y) + q2 * (kv.z + t4.z) + q3 * (kv.w + t4.w);
            s += __shfl_xor(s, 1, 64);
            s += __shfl_xor(s, 2, 64);
            s += __shfl_xor(s, 4, 64);
            s += __shfl_xor(s, 8, 64);
            if ((lane & 15) == 0) p[h][k] = s * 0.125f;
        }
    }
    __syncthreads();

    // --- softmax: wave w owns head w; invalid k (> qpos) masked at read
    {
        float* ph = &p[w][0];
        float v0 = (lane       <= qpos) ? ph[lane      ] : BIG_NEG_F;
        float v1 = (lane + 64  <= qpos) ? ph[lane + 64 ] : BIG_NEG_F;
        float v2 = (lane + 128 <= qpos) ? ph[lane + 128] : BIG_NEG_F;
        float v3 = (lane + 192 <= qpos) ? ph[lane + 192] : BIG_NEG_F;
        float mx = wave_max(fmaxf(fmaxf(v0, v1), fmaxf(v2, v3)));
        float e0 = __expf(v0 - mx), e1 = __expf(v1 - mx), e2 = __expf(v2 - mx), e3 = __expf(v3 - mx);
        ph[lane] = e0; ph[lane + 64] = e1; ph[lane + 128] = e2; ph[lane + 192] = e3;
        float ssum = wave_sum(e0 + e1 + e2 + e3);
        if (lane == 0) denom[w] = ssum;
    }
    __syncthreads();

    // --- phase 3: PV, batch-2 with independent accumulators
    {
        int hh = lane >> 4;                 // head of this lane's 4 dims
        const float* Vb  = Vp + (size_t)(b << 8) * 256 + lane * 4;
        const float* tVb = tV + lane * 4;
        const float* prow = &p[hh][0];
        float4 a0 = {0.f, 0.f, 0.f, 0.f}, a1 = a0;
        int cnt = (qpos >= w) ? ((qpos - w) >> 2) + 1 : 0;
        int i = 0;
        for (; i + 2 <= cnt; i += 2) {
            int k0 = w + 4 * i;
            float p0 = prow[k0], p1 = prow[k0 + 4];
            float4 v0 = *(const float4*)(Vb + (k0    ) * 256);
            float4 v1 = *(const float4*)(Vb + (k0 + 4) * 256);
            float4 u0 = *(const float4*)(tVb + stm[k0    ] * 256);
            float4 u1 = *(const float4*)(tVb + stm[k0 + 4] * 256);
            a0.x += p0 * (v0.x + u0.x); a0.y += p0 * (v0.y + u0.y); a0.z += p0 * (v0.z + u0.z); a0.w += p0 * (v0.w + u0.w);
            a1.x += p1 * (v1.x + u1.x); a1.y += p1 * (v1.y + u1.y); a1.z += p1 * (v1.z + u1.z); a1.w += p1 * (v1.w + u1.w);
        }
        if (i < cnt) {
            int k2 = w + 4 * i;
            float pk = prow[k2];
            float4 v = *(const float4*)(Vb + k2 * 256);
            float4 t = *(const float4*)(tVb + stm[k2] * 256);
            a0.x += pk * (v.x + t.x);
            a0.y += pk * (v.y + t.y);
            a0.z += pk * (v.z + t.z);
            a0.w += pk * (v.w + t.w);
        }
        float4 o;
        o.x = a0.x + a1.x;
        o.y = a0.y + a1.y;
        o.z = a0.z + a1.z;
        o.w = a0.w + a1.w;
        *(float4*)&opart[w][lane * 4] = o;
    }
    __syncthreads();

    // --- combine + fused ln2; emit x2 fp32 + bf16 hi/lo
    {
        int d = tid, h = tid >> 6;
        float tot = opart[0][d] + opart[1][d] + opart[2][d] + opart[3][d];
        float xv = qres[rowbase + d] + tot / denom[h];
        float s = wave_sum(xv);
        if (lane == 0) lnws[w] = s;
        __syncthreads();
        float mean = (lnws[0] + lnws[1] + lnws[2] + lnws[3]) * (1.f / 256.f);
        float dd = xv - mean;
        float s2 = wave_sum(dd * dd);
        if (lane == 0) lnws[4 + w] = s2;
        __syncthreads();
        float var = (lnws[4] + lnws[5] + lnws[6] + lnws[7]) * (1.f / 256.f);
        float outv = dd / sqrtf(var + 1e-8f) * g2[d] + b2[d];
        X2[rowbase + d] = outv;
        split1(outv, &X2h[rowbase + d], &X2l[rowbase + d]);
    }
}

extern "C" void kernel_launch(void* const* d_in, const int* in_sizes, int n_in,
                              void* d_out, int out_size, void* d_ws, size_t ws_size,
                              hipStream_t stream) {
    const unsigned char* mask_raw = (const unsigned char*)d_in[0];
    const float* seq  = (const float*)d_in[1];
    const int*   tm   = (const int*)d_in[3];
    const float* Wq   = (const float*)d_in[5];
    const float* bq   = (const float*)d_in[6];
    const float* Wk   = (const float*)d_in[7];
    const float* bk   = (const float*)d_in[8];
    const float* Wv   = (const float*)d_in[9];
    const float* bv   = (const float*)d_in[10];
    const float* ln1g = (const float*)d_in[11];
    const float* ln1b = (const float*)d_in[12];
    const float* ln2g = (const float*)d_in[13];
    const float* ln2b = (const float*)d_in[14];
    const float* W1   = (const float*)d_in[15];
    const float* b1   = (const float*)d_in[16];
    const float* W2   = (const float*)d_in[17];
    const float* b2   = (const float*)d_in[18];
    const float* posK = (const float*)d_in[19];
    const float* posV = (const float*)d_in[20];
    const float* tK   = (const float*)d_in[21];
    const float* tV   = (const float*)d_in[22];
    const float* lnfg = (const float*)d_in[23];
    const float* lnfb = (const float*)d_in[24];

    const int NEL = 8 * 256 * 256;        // 524288 elements
    const int WEL = 2 * 256 * 256;        // 131072 elements per weight tensor
    float* x   = (float*)d_ws;
    float* q   = x   + NEL;
    float* Qb  = q   + NEL;
    float* KpB = Qb  + NEL;
    float* VpB = KpB + NEL;
    float* x2  = VpB + NEL;
    float* hb  = x2  + NEL;
    unsigned char* mask = (unsigned char*)(hb + NEL);
    unsigned short* us = (unsigned short*)(mask + 2048);
    unsigned short* qh  = us;            unsigned short* ql  = qh  + NEL;
    unsigned short* xh  = ql  + NEL;     unsigned short* xl  = xh  + NEL;
    unsigned short* x2h = xl  + NEL;     unsigned short* x2l = x2h + NEL;
    unsigned short* hbh = x2l + NEL;     unsigned short* hbl = hbh + NEL;
    unsigned short* wsp = hbl + NEL;
    unsigned short* WqH = wsp;           unsigned short* WqL = WqH + WEL;
    unsigned short* WkH = WqL + WEL;     unsigned short* WkL = WkH + WEL;
    unsigned short* WvH = WkL + WEL;     unsigned short* WvL = WvH + WEL;
    unsigned short* W1H = WvL + WEL;     unsigned short* W1L = W1H + WEL;
    unsigned short* W2H = W1L + WEL;     unsigned short* W2L = W2H + WEL;

    dim3 gSplit(128, 1, 5);
    dim3 gQKV(16, 32, 3);   // 1536 blocks, 24 waves/CU
    dim3 gFFN(16, 32, 1);   // 512 blocks, 8 waves/CU

    SplitJob sq = {Wq, WqH, WqL}, sk = {Wk, WkH, WkL}, sv = {Wv, WvH, WvL};
    SplitJob s1 = {W1, W1H, W1L}, s2 = {W2, W2H, W2L};
    splitw_kernel<<<gSplit, 256, 0, stream>>>(sq, sk, sv, s1, s2);
    prep_ln_kernel<<<2048, 256, 0, stream>>>(seq, mask_raw, mask, x, q, ln1g, ln1b,
                                             xh, xl, qh, ql);
    for (int blk = 0; blk < 2; ++blk) {
        int o1 = blk * 256, oW = blk * 256 * 256;
        GemmJob jq = {qh, ql, WqH + oW, WqL + oW, bq + o1, nullptr, nullptr, nullptr,
                      Qb, nullptr, nullptr, 0};
        GemmJob jk = {xh, xl, WkH + oW, WkL + oW, bk + o1, posK, nullptr, nullptr,
                      KpB, nullptr, nullptr, 0};
        GemmJob jv = {xh, xl, WvH + oW, WvL + oW, bv + o1, posV, nullptr, nullptr,
                      VpB, nullptr, nullptr, 0};
        gemm_frag_kernel<<<gQKV, 256, 0, stream>>>(jq, jk, jv);
        attn_kernel<<<2048, 256, 0, stream>>>(Qb, KpB, VpB, q, tm, tK, tV,
                                              ln2g + o1, ln2b + o1, x2, x2h, x2l);
        GemmJob f1 = {x2h, x2l, W1H + oW, W1L + oW, b1 + o1, nullptr, nullptr, nullptr,
                      hb, hbh, hbl, 1};
        gemm_frag_kernel<<<gFFN, 256, 0, stream>>>(f1, f1, f1);
        GemmJob f2 = {hbh, hbl, W2H + oW, W2L + oW, b2 + o1, nullptr, x2, mask,
                      x, xh, xl, 0};
        gemm_frag_kernel<<<gFFN, 256, 0, stream>>>(f2, f2, f2);
        if (blk == 0) ln_kernel<<<2048, 256, 0, stream>>>(x, q, ln1g + 256, ln1b + 256,
                                                          qh, ql);
    }
    ln_kernel<<<2048, 256, 0, stream>>>(x, (float*)d_out, lnfg, lnfb, nullptr, nullptr);
}

// Round 13
// 257.791 us; speedup vs baseline: 1.1017x; 1.1017x over previous
//
#include <hip/hip_runtime.h>

#define BIG_NEG_F (-4294967296.0f)

typedef __attribute__((ext_vector_type(8))) short bf16x8;
typedef __attribute__((ext_vector_type(4))) float f32x4;

__device__ __forceinline__ float wave_sum(float v) {
#pragma unroll
    for (int m = 32; m; m >>= 1) v += __shfl_xor(v, m, 64);
    return v;
}
__device__ __forceinline__ float wave_max(float v) {
#pragma unroll
    for (int m = 32; m; m >>= 1) v = fmaxf(v, __shfl_xor(v, m, 64));
    return v;
}

__device__ __forceinline__ unsigned int pack2(float a, float b) {
    return (__float_as_uint(b) & 0xffff0000u) | (__float_as_uint(a) >> 16);
}
__device__ __forceinline__ float hipart(float x) {
    return __uint_as_float(__float_as_uint(x) & 0xffff0000u);
}
// truncation split: hi = bf16-truncate(v), lo = bf16-truncate(v - hi). Same math as r11/r12.
__device__ __forceinline__ void split1(float v, unsigned short* hp, unsigned short* lp) {
    unsigned int hu = __float_as_uint(v) & 0xffff0000u;
    *hp = (unsigned short)(hu >> 16);
    *lp = (unsigned short)(__float_as_uint(v - __uint_as_float(hu)) >> 16);
}

// Fused: detect mask layout, x = seq*keep, q = ln1(x); also emit bf16 hi/lo pairs of
// x and q (GEMM operands). One block per row.
__global__ __launch_bounds__(256) void prep_ln_kernel(const float* __restrict__ seq,
                                                      const unsigned char* __restrict__ mraw,
                                                      unsigned char* __restrict__ mout,
                                                      float* __restrict__ X, float* __restrict__ Q,
                                                      const float* __restrict__ g,
                                                      const float* __restrict__ be,
                                                      unsigned short* __restrict__ Xh,
                                                      unsigned short* __restrict__ Xl,
                                                      unsigned short* __restrict__ Qh,
                                                      unsigned short* __restrict__ Ql) {
    __shared__ int flags[2];
    __shared__ float ws[8];
    int row = blockIdx.x, tid = threadIdx.x;
    if (tid == 0) { flags[0] = 0; flags[1] = 0; }
    __syncthreads();
    for (int i = tid; i < 2048; i += 256) {
        if (mraw[i]) {
            if (i & 3) atomicOr(&flags[0], 1);
            else if (i & 4) atomicOr(&flags[1], 1);
        }
    }
    __syncthreads();
    int mode = flags[0] ? 0 : (flags[1] ? 1 : 2);  // 0=u8, 1=i32, 2=i64
    unsigned char mrow = (mode == 0) ? mraw[row] : (mode == 1) ? mraw[row * 4] : mraw[row * 8];
    if (tid == 0) mout[row] = mrow ? 1 : 0;
    int idx = row * 256 + tid;
    int w = tid >> 6, lane = tid & 63;
    float v = mrow ? 0.f : seq[idx];
    X[idx] = v;
    split1(v, &Xh[idx], &Xl[idx]);
    float s = wave_sum(v);
    if (lane == 0) ws[w] = s;
    __syncthreads();
    float mean = (ws[0] + ws[1] + ws[2] + ws[3]) * (1.f / 256.f);
    float d = v - mean;
    float s2 = wave_sum(d * d);
    if (lane == 0) ws[4 + w] = s2;
    __syncthreads();
    float var = (ws[4] + ws[5] + ws[6] + ws[7]) * (1.f / 256.f);
    float qv = d / sqrtf(var + 1e-8f) * g[tid] + be[tid];
    Q[idx] = qv;
    split1(qv, &Qh[idx], &Ql[idx]);
}

// row layernorm over H=256; optional bf16 hi/lo outputs (null for final LN).
__global__ __launch_bounds__(256) void ln_kernel(const float* __restrict__ X, float* __restrict__ Y,
                                                 const float* __restrict__ g,
                                                 const float* __restrict__ be,
                                                 unsigned short* __restrict__ Yh,
                                                 unsigned short* __restrict__ Yl) {
    __shared__ float ws[8];
    int row = blockIdx.x, tid = threadIdx.x;
    int idx = row * 256 + tid;
    int w = tid >> 6, lane = tid & 63;
    float v = X[idx];
    float s = wave_sum(v);
    if (lane == 0) ws[w] = s;
    __syncthreads();
    float mean = (ws[0] + ws[1] + ws[2] + ws[3]) * (1.f / 256.f);
    float d = v - mean;
    float s2 = wave_sum(d * d);
    if (lane == 0) ws[4 + w] = s2;
    __syncthreads();
    float var = (ws[4] + ws[5] + ws[6] + ws[7]) * (1.f / 256.f);
    float yv = d / sqrtf(var + 1e-8f) * g[tid] + be[tid];
    Y[idx] = yv;
    if (Yh) split1(yv, &Yh[idx], &Yl[idx]);
}

struct SplitJob { const float* src; unsigned short* h; unsigned short* l; };

// Split the 5 weight tensors ([2,256,256] each) into bf16 hi/lo. grid (128,1,5).
__global__ __launch_bounds__(256) void splitw_kernel(SplitJob s0, SplitJob s1, SplitJob s2,
                                                     SplitJob s3, SplitJob s4) {
    SplitJob S = (blockIdx.z == 0) ? s0 : (blockIdx.z == 1) ? s1 : (blockIdx.z == 2) ? s2
               : (blockIdx.z == 3) ? s3 : s4;
    int i = (blockIdx.x * 256 + threadIdx.x) * 4;
    float4 v = *(const float4*)(S.src + i);
    uint2 h, l;
    h.x = pack2(v.x, v.y); h.y = pack2(v.z, v.w);
    l.x = pack2(v.x - hipart(v.x), v.y - hipart(v.y));
    l.y = pack2(v.z - hipart(v.z), v.w - hipart(v.w));
    *(uint2*)(S.h + i) = h;
    *(uint2*)(S.l + i) = l;
}

struct GemmJob {
    const unsigned short* Ah;  // [2048,256] bf16-hi
    const unsigned short* Al;
    const unsigned short* Wh;  // [256,256] (out,in) bf16-hi
    const unsigned short* Wl;
    const float* bias;
    const float* pos;          // per-position add, or null
    const float* res;          // residual add, or null
    const unsigned char* maskm;
    float* C;
    unsigned short* Ch;        // optional bf16 outputs (next GEMM's A operand)
    unsigned short* Cl;
    int relu;
};

// MFMA GEMM, r11 LDS-staged structure + PRE-SPLIT operands (r12's lesson: direct
// per-fragment global loads are transaction-bound — 16 scattered 64B txns per load;
// block-cooperative staging keeps loads wide/coalesced). Staging is now a pure uint4
// copy: no split VALU in the hot loop (r11 burned ~190 VALU ops/thread/K-tile on
// splitting, and re-split W 32x per dispatch). 64x64 tile, BK=64, 4 waves as 2x2;
// split-precision A·B ≈ Ah·Bh + Ah·Bl + Al·Bh (rel err ~2^-16). Fragment layouts
// HW-verified r11. LDS rows padded to 72 ushorts (144B = 9x16B). Register-prefetch
// of next K-tile under the MFMAs.
__global__ __launch_bounds__(256) void gemm_mfma_kernel(GemmJob j0, GemmJob j1, GemmJob j2) {
    GemmJob J = (blockIdx.z == 0) ? j0 : (blockIdx.z == 1 ? j1 : j2);
    __shared__ unsigned short Ah[64][72], Al[64][72], Wh[64][72], Wl[64][72];
    int tid = threadIdx.x;
    int n0 = blockIdx.x * 64, m0 = blockIdx.y * 64;
    int w = tid >> 6, lane = tid & 63;
    int wm = w >> 1, wn = w & 1;
    int srow = tid >> 2, sq = tid & 3;          // staging: row 0..63, k-quarter (16 ushorts)
    const unsigned short* Asrc_h = J.Ah + (m0 + srow) * 256 + sq * 16;
    const unsigned short* Asrc_l = J.Al + (m0 + srow) * 256 + sq * 16;
    const unsigned short* Wsrc_h = J.Wh + (n0 + srow) * 256 + sq * 16;
    const unsigned short* Wsrc_l = J.Wl + (n0 + srow) * 256 + sq * 16;
    uint4 ah0 = *(const uint4*)(Asrc_h), ah1 = *(const uint4*)(Asrc_h + 8);
    uint4 al0 = *(const uint4*)(Asrc_l), al1 = *(const uint4*)(Asrc_l + 8);
    uint4 wh0 = *(const uint4*)(Wsrc_h), wh1 = *(const uint4*)(Wsrc_h + 8);
    uint4 wl0 = *(const uint4*)(Wsrc_l), wl1 = *(const uint4*)(Wsrc_l + 8);
    f32x4 acc[2][2] = {};
    int r15 = lane & 15, hgrp = (lane >> 4) << 3;
    for (int kt = 0; kt < 4; ++kt) {
        if (kt) __syncthreads();                // previous compute done before overwrite
        *(uint4*)&Ah[srow][sq * 16]     = ah0;  *(uint4*)&Ah[srow][sq * 16 + 8] = ah1;
        *(uint4*)&Al[srow][sq * 16]     = al0;  *(uint4*)&Al[srow][sq * 16 + 8] = al1;
        *(uint4*)&Wh[srow][sq * 16]     = wh0;  *(uint4*)&Wh[srow][sq * 16 + 8] = wh1;
        *(uint4*)&Wl[srow][sq * 16]     = wl0;  *(uint4*)&Wl[srow][sq * 16 + 8] = wl1;
        __syncthreads();
        if (kt < 3) {                           // prefetch next K-tile; retires under MFMAs
            int ko = (kt + 1) * 64;
            ah0 = *(const uint4*)(Asrc_h + ko); ah1 = *(const uint4*)(Asrc_h + ko + 8);
            al0 = *(const uint4*)(Asrc_l + ko); al1 = *(const uint4*)(Asrc_l + ko + 8);
            wh0 = *(const uint4*)(Wsrc_h + ko); wh1 = *(const uint4*)(Wsrc_h + ko + 8);
            wl0 = *(const uint4*)(Wsrc_l + ko); wl1 = *(const uint4*)(Wsrc_l + ko + 8);
        }
#pragma unroll
        for (int s = 0; s < 2; ++s) {
            int ko = s * 32 + hgrp;
            bf16x8 fah0 = *(const bf16x8*)&Ah[wm * 32 + r15][ko];
            bf16x8 fah1 = *(const bf16x8*)&Ah[wm * 32 + 16 + r15][ko];
            bf16x8 fal0 = *(const bf16x8*)&Al[wm * 32 + r15][ko];
            bf16x8 fal1 = *(const bf16x8*)&Al[wm * 32 + 16 + r15][ko];
            bf16x8 fbh0 = *(const bf16x8*)&Wh[wn * 32 + r15][ko];
            bf16x8 fbh1 = *(const bf16x8*)&Wh[wn * 32 + 16 + r15][ko];
            bf16x8 fbl0 = *(const bf16x8*)&Wl[wn * 32 + r15][ko];
            bf16x8 fbl1 = *(const bf16x8*)&Wl[wn * 32 + 16 + r15][ko];
            acc[0][0] = __builtin_amdgcn_mfma_f32_16x16x32_bf16(fah0, fbh0, acc[0][0], 0, 0, 0);
            acc[0][0] = __builtin_amdgcn_mfma_f32_16x16x32_bf16(fah0, fbl0, acc[0][0], 0, 0, 0);
            acc[0][0] = __builtin_amdgcn_mfma_f32_16x16x32_bf16(fal0, fbh0, acc[0][0], 0, 0, 0);
            acc[0][1] = __builtin_amdgcn_mfma_f32_16x16x32_bf16(fah0, fbh1, acc[0][1], 0, 0, 0);
            acc[0][1] = __builtin_amdgcn_mfma_f32_16x16x32_bf16(fah0, fbl1, acc[0][1], 0, 0, 0);
            acc[0][1] = __builtin_amdgcn_mfma_f32_16x16x32_bf16(fal0, fbh1, acc[0][1], 0, 0, 0);
            acc[1][0] = __builtin_amdgcn_mfma_f32_16x16x32_bf16(fah1, fbh0, acc[1][0], 0, 0, 0);
            acc[1][0] = __builtin_amdgcn_mfma_f32_16x16x32_bf16(fah1, fbl0, acc[1][0], 0, 0, 0);
            acc[1][0] = __builtin_amdgcn_mfma_f32_16x16x32_bf16(fal1, fbh0, acc[1][0], 0, 0, 0);
            acc[1][1] = __builtin_amdgcn_mfma_f32_16x16x32_bf16(fah1, fbh1, acc[1][1], 0, 0, 0);
            acc[1][1] = __builtin_amdgcn_mfma_f32_16x16x32_bf16(fah1, fbl1, acc[1][1], 0, 0, 0);
            acc[1][1] = __builtin_amdgcn_mfma_f32_16x16x32_bf16(fal1, fbh1, acc[1][1], 0, 0, 0);
        }
    }
    // epilogue: C/D layout col=lane&15, row=(lane>>4)*4+rr
#pragma unroll
    for (int mf = 0; mf < 2; ++mf) {
#pragma unroll
        for (int nf = 0; nf < 2; ++nf) {
            int col = n0 + wn * 32 + nf * 16 + r15;
            int rowb = m0 + wm * 32 + mf * 16 + ((lane >> 4) << 2);
            float bcol = J.bias[col];
            f32x4 a = acc[mf][nf];
#pragma unroll
            for (int rr = 0; rr < 4; ++rr) {
                int m = rowb + rr;
                float v = a[rr] + bcol;
                if (J.pos) v += J.pos[(m & 255) * 256 + col];
                if (J.relu) v = fmaxf(v, 0.f);
                if (J.res) v += J.res[m * 256 + col];
                if (J.maskm && J.maskm[m]) v = 0.f;
                J.C[m * 256 + col] = v;
                if (J.Ch) split1(v, &J.Ch[m * 256 + col], &J.Cl[m * 256 + col]);
            }
        }
    }
}

// 2048 one-qpos blocks. b = bid&7 keeps XCD affinity (working set ~2.3MB fits 4MiB
// private L2). qpos map per-CU balanced (each CU's 8 blocks sum to 1028 rows).
// Batch-2 inner loops: fits 64-VGPR budget of (256,8) with no scratch (batch-4
// spills — verified r1/2/4/6). Epilogue also emits x2 bf16 hi/lo.
__global__ __launch_bounds__(256, 8) void attn_kernel(
    const float* __restrict__ Q, const float* __restrict__ Kp, const float* __restrict__ Vp,
    const float* __restrict__ qres, const int* __restrict__ tm,
    const float* __restrict__ tK, const float* __restrict__ tV,
    const float* __restrict__ g2, const float* __restrict__ b2,
    float* __restrict__ X2, unsigned short* __restrict__ X2h,
    unsigned short* __restrict__ X2l) {
    int bid = (int)blockIdx.x;
    int b = bid & 7;                    // XCD-aligned batch
    int i6 = bid >> 3;                  // 0..255
    int jj6 = i6 & 31, a6 = i6 >> 5;
    int q0m = jj6 * 4 + (a6 >> 1);      // 0..127
    int qpos = (a6 & 1) ? q0m : 255 - q0m;
    int tid = threadIdx.x, w = tid >> 6, lane = tid & 63;
    __shared__ float qrow[256];
    __shared__ int   stm[256];
    __shared__ float p[4][264];     // 264: writer lanes spread banks
    __shared__ float opart[4][256];
    __shared__ float denom[4];
    __shared__ float lnws[8];

    int rowbase = (b * 256 + qpos) * 256;
    qrow[tid] = Q[rowbase + tid];
    {
        int t = tm[rowbase + tid];
        stm[tid] = t < 0 ? 0 : (t > 512 ? 512 : t);
    }
    __syncthreads();

    // --- phase 1: scores, k ≡ w (mod 4) per wave — balanced across waves; batch-2
    {
        int h = lane >> 4;
        const float* qr = qrow + lane * 4;
        float q0 = qr[0], q1 = qr[1], q2 = qr[2], q3 = qr[3];
        const float* Kb  = Kp + (size_t)(b << 8) * 256 + lane * 4;
        const float* tKb = tK + lane * 4;
        int nact = (qpos >= w) ? ((qpos - w) >> 2) + 1 : 0;  // #k in {w, w+4, ...} <= qpos
        int i = 0;
        for (; i + 2 <= nact; i += 2) {
            int k0 = w + 4 * i;          // rows k0, k0+4
            float4 kv0 = *(const float4*)(Kb + (k0    ) * 256);
            float4 kv1 = *(const float4*)(Kb + (k0 + 4) * 256);
            float4 t0 = *(const float4*)(tKb + stm[k0    ] * 256);
            float4 t1 = *(const float4*)(tKb + stm[k0 + 4] * 256);
            float s0 = q0 * (kv0.x + t0.x) + q1 * (kv0.y + t0.y) + q2 * (kv0.z + t0.z) + q3 * (kv0.w + t0.w);
            float s1 = q0 * (kv1.x + t1.x) + q1 * (kv1.y + t1.y) + q2 * (kv1.z + t1.z) + q3 * (kv1.w + t1.w);
            s0 += __shfl_xor(s0, 1, 64); s1 += __shfl_xor(s1, 1, 64);
            s0 += __shfl_xor(s0, 2, 64); s1 += __shfl_xor(s1, 2, 64);
            s0 += __shfl_xor(s0, 4, 64); s1 += __shfl_xor(s1, 4, 64);
            s0 += __shfl_xor(s0, 8, 64); s1 += __shfl_xor(s1, 8, 64);
            if ((lane & 15) == 0) {
                p[h][k0    ] = s0 * 0.125f;
                p[h][k0 + 4] = s1 * 0.125f;
            }
        }
        if (i < nact) {
            int k = w + 4 * i;
            float4 kv = *(const float4*)(Kb + k * 256);
            float4 t4 = *(const float4*)(tKb + stm[k] * 256);
            float s = q0 * (kv.x + t4.x) + q1 * (kv.y + t4.y) + q2 * (kv.z + t4.z) + q3 * (kv.w + t4.w);
            s += __shfl_xor(s, 1, 64);
            s += __shfl_xor(s, 2, 64);
            s += __shfl_xor(s, 4, 64);
            s += __shfl_xor(s, 8, 64);
            if ((lane & 15) == 0) p[h][k] = s * 0.125f;
        }
    }
    __syncthreads();

    // --- softmax: wave w owns head w; invalid k (> qpos) masked at read
    {
        float* ph = &p[w][0];
        float v0 = (lane       <= qpos) ? ph[lane      ] : BIG_NEG_F;
        float v1 = (lane + 64  <= qpos) ? ph[lane + 64 ] : BIG_NEG_F;
        float v2 = (lane + 128 <= qpos) ? ph[lane + 128] : BIG_NEG_F;
        float v3 = (lane + 192 <= qpos) ? ph[lane + 192] : BIG_NEG_F;
        float mx = wave_max(fmaxf(fmaxf(v0, v1), fmaxf(v2, v3)));
        float e0 = __expf(v0 - mx), e1 = __expf(v1 - mx), e2 = __expf(v2 - mx), e3 = __expf(v3 - mx);
        ph[lane] = e0; ph[lane + 64] = e1; ph[lane + 128] = e2; ph[lane + 192] = e3;
        float ssum = wave_sum(e0 + e1 + e2 + e3);
        if (lane == 0) denom[w] = ssum;
    }
    __syncthreads();

    // --- phase 3: PV, batch-2 with independent accumulators
    {
        int hh = lane >> 4;                 // head of this lane's 4 dims
        const float* Vb  = Vp + (size_t)(b << 8) * 256 + lane * 4;
        const float* tVb = tV + lane * 4;
        const float* prow = &p[hh][0];
        float4 a0 = {0.f, 0.f, 0.f, 0.f}, a1 = a0;
        int cnt = (qpos >= w) ? ((qpos - w) >> 2) + 1 : 0;
        int i = 0;
        for (; i + 2 <= cnt; i += 2) {
            int k0 = w + 4 * i;
            float p0 = prow[k0], p1 = prow[k0 + 4];
            float4 v0 = *(const float4*)(Vb + (k0    ) * 256);
            float4 v1 = *(const float4*)(Vb + (k0 + 4) * 256);
            float4 u0 = *(const float4*)(tVb + stm[k0    ] * 256);
            float4 u1 = *(const float4*)(tVb + stm[k0 + 4] * 256);
            a0.x += p0 * (v0.x + u0.x); a0.y += p0 * (v0.y + u0.y); a0.z += p0 * (v0.z + u0.z); a0.w += p0 * (v0.w + u0.w);
            a1.x += p1 * (v1.x + u1.x); a1.y += p1 * (v1.y + u1.y); a1.z += p1 * (v1.z + u1.z); a1.w += p1 * (v1.w + u1.w);
        }
        if (i < cnt) {
            int k2 = w + 4 * i;
            float pk = prow[k2];
            float4 v = *(const float4*)(Vb + k2 * 256);
            float4 t = *(const float4*)(tVb + stm[k2] * 256);
            a0.x += pk * (v.x + t.x);
            a0.y += pk * (v.y + t.y);
            a0.z += pk * (v.z + t.z);
            a0.w += pk * (v.w + t.w);
        }
        float4 o;
        o.x = a0.x + a1.x;
        o.y = a0.y + a1.y;
        o.z = a0.z + a1.z;
        o.w = a0.w + a1.w;
        *(float4*)&opart[w][lane * 4] = o;
    }
    __syncthreads();

    // --- combine + fused ln2; emit x2 fp32 + bf16 hi/lo
    {
        int d = tid, h = tid >> 6;
        float tot = opart[0][d] + opart[1][d] + opart[2][d] + opart[3][d];
        float xv = qres[rowbase + d] + tot / denom[h];
        float s = wave_sum(xv);
        if (lane == 0) lnws[w] = s;
        __syncthreads();
        float mean = (lnws[0] + lnws[1] + lnws[2] + lnws[3]) * (1.f / 256.f);
        float dd = xv - mean;
        float s2 = wave_sum(dd * dd);
        if (lane == 0) lnws[4 + w] = s2;
        __syncthreads();
        float var = (lnws[4] + lnws[5] + lnws[6] + lnws[7]) * (1.f / 256.f);
        float outv = dd / sqrtf(var + 1e-8f) * g2[d] + b2[d];
        X2[rowbase + d] = outv;
        split1(outv, &X2h[rowbase + d], &X2l[rowbase + d]);
    }
}

extern "C" void kernel_launch(void* const* d_in, const int* in_sizes, int n_in,
                              void* d_out, int out_size, void* d_ws, size_t ws_size,
                              hipStream_t stream) {
    const unsigned char* mask_raw = (const unsigned char*)d_in[0];
    const float* seq  = (const float*)d_in[1];
    const int*   tm   = (const int*)d_in[3];
    const float* Wq   = (const float*)d_in[5];
    const float* bq   = (const float*)d_in[6];
    const float* Wk   = (const float*)d_in[7];
    const float* bk   = (const float*)d_in[8];
    const float* Wv   = (const float*)d_in[9];
    const float* bv   = (const float*)d_in[10];
    const float* ln1g = (const float*)d_in[11];
    const float* ln1b = (const float*)d_in[12];
    const float* ln2g = (const float*)d_in[13];
    const float* ln2b = (const float*)d_in[14];
    const float* W1   = (const float*)d_in[15];
    const float* b1   = (const float*)d_in[16];
    const float* W2   = (const float*)d_in[17];
    const float* b2   = (const float*)d_in[18];
    const float* posK = (const float*)d_in[19];
    const float* posV = (const float*)d_in[20];
    const float* tK   = (const float*)d_in[21];
    const float* tV   = (const float*)d_in[22];
    const float* lnfg = (const float*)d_in[23];
    const float* lnfb = (const float*)d_in[24];

    const int NEL = 8 * 256 * 256;        // 524288 elements
    const int WEL = 2 * 256 * 256;        // 131072 elements per weight tensor
    float* x   = (float*)d_ws;
    float* q   = x   + NEL;
    float* Qb  = q   + NEL;
    float* KpB = Qb  + NEL;
    float* VpB = KpB + NEL;
    float* x2  = VpB + NEL;
    float* hb  = x2  + NEL;
    unsigned char* mask = (unsigned char*)(hb + NEL);
    unsigned short* us = (unsigned short*)(mask + 2048);
    unsigned short* qh  = us;            unsigned short* ql  = qh  + NEL;
    unsigned short* xh  = ql  + NEL;     unsigned short* xl  = xh  + NEL;
    unsigned short* x2h = xl  + NEL;     unsigned short* x2l = x2h + NEL;
    unsigned short* hbh = x2l + NEL;     unsigned short* hbl = hbh + NEL;
    unsigned short* wsp = hbl + NEL;
    unsigned short* WqH = wsp;           unsigned short* WqL = WqH + WEL;
    unsigned short* WkH = WqL + WEL;     unsigned short* WkL = WkH + WEL;
    unsigned short* WvH = WkL + WEL;     unsigned short* WvL = WvH + WEL;
    unsigned short* W1H = WvL + WEL;     unsigned short* W1L = W1H + WEL;
    unsigned short* W2H = W1L + WEL;     unsigned short* W2L = W2H + WEL;

    dim3 gSplit(128, 1, 5);
    dim3 gQKV(4, 32, 3);   // 64x64 tiles, 384 blocks
    dim3 gFFN(4, 32, 1);   // 128 blocks

    SplitJob sq = {Wq, WqH, WqL}, sk = {Wk, WkH, WkL}, sv = {Wv, WvH, WvL};
    SplitJob s1 = {W1, W1H, W1L}, s2 = {W2, W2H, W2L};
    splitw_kernel<<<gSplit, 256, 0, stream>>>(sq, sk, sv, s1, s2);
    prep_ln_kernel<<<2048, 256, 0, stream>>>(seq, mask_raw, mask, x, q, ln1g, ln1b,
                                             xh, xl, qh, ql);
    for (int blk = 0; blk < 2; ++blk) {
        int o1 = blk * 256, oW = blk * 256 * 256;
        GemmJob jq = {qh, ql, WqH + oW, WqL + oW, bq + o1, nullptr, nullptr, nullptr,
                      Qb, nullptr, nullptr, 0};
        GemmJob jk = {xh, xl, WkH + oW, WkL + oW, bk + o1, posK, nullptr, nullptr,
                      KpB, nullptr, nullptr, 0};
        GemmJob jv = {xh, xl, WvH + oW, WvL + oW, bv + o1, posV, nullptr, nullptr,
                      VpB, nullptr, nullptr, 0};
        gemm_mfma_kernel<<<gQKV, 256, 0, stream>>>(jq, jk, jv);
        attn_kernel<<<2048, 256, 0, stream>>>(Qb, KpB, VpB, q, tm, tK, tV,
                                              ln2g + o1, ln2b + o1, x2, x2h, x2l);
        GemmJob f1 = {x2h, x2l, W1H + oW, W1L + oW, b1 + o1, nullptr, nullptr, nullptr,
                      hb, hbh, hbl, 1};
        gemm_mfma_kernel<<<gFFN, 256, 0, stream>>>(f1, f1, f1);
        GemmJob f2 = {hbh, hbl, W2H + oW, W2L + oW, b2 + o1, nullptr, x2, mask,
                      x, xh, xl, 0};
        gemm_mfma_kernel<<<gFFN, 256, 0, stream>>>(f2, f2, f2);
        if (blk == 0) ln_kernel<<<2048, 256, 0, stream>>>(x, q, ln1g + 256, ln1b + 256,
                                                          qh, ql);
    }
    ln_kernel<<<2048, 256, 0, stream>>>(x, (float*)d_out, lnfg, lnfb, nullptr, nullptr);
}